// Round 12
// baseline (232.512 us; speedup 1.0000x reference)
//
#include <hip/hip_runtime.h>
#include <stdint.h>

// Problem constants (fixed by setup_inputs)
#define N_    8
#define A_    15
#define H_    256
#define W_    256
#define M_    (A_*H_*W_)      // 983040 anchors per image
#define BINS  8192
#define BSH   19              // ord32 >> 19 = top 13 bits
#define KMAJ  3200            // raw-count threshold margin over K=2000
#define CAP   8192            // candidate capacity per image
#define CBUF  2048            // per-block LDS candidate buffer
#define WPR   32              // words per keep-row = ceil(2000/64)
#define CH    128             // NMS rows per chunk (R11: halves barrier count)

__device__ __constant__ double CLIP_  = 4.135166556742356;  // log(1000/16) in f64
__device__ __constant__ double IMG_   = 1024.0;
__device__ __constant__ double MINSZ_ = 1.0;
__device__ __constant__ double NMST_  = 0.7;

__device__ __forceinline__ uint32_t ord32(float s) {
    uint32_t u = __float_as_uint(s);
    return u ^ (uint32_t)(((int32_t)u >> 31) | 0x80000000u);
}

// f64 decode exactly mirroring the reference formula order (unchanged — passing)
__device__ __forceinline__ void decode_box(
    const float* __restrict__ breg, const float* __restrict__ anchors,
    int n, int a, int hw, int m,
    double& x1, double& y1, double& x2, double& y2)
{
    size_t bbase = ((size_t)(n*60 + a*4)) * 65536 + (size_t)hw;
    double d0 = (double)breg[bbase];
    double d1 = (double)breg[bbase + 65536];
    double d2 = (double)breg[bbase + 2*65536];
    double d3 = (double)breg[bbase + 3*65536];
    float4 av = *reinterpret_cast<const float4*>(anchors + (size_t)m*4);
    double a0 = (double)av.x, a1 = (double)av.y, a2 = (double)av.z, a3 = (double)av.w;
    double ww = a2 - a0, hh = a3 - a1;
    double cx = a0 + 0.5*ww, cy = a1 + 0.5*hh;
    double dw = fmin(d2, CLIP_), dh = fmin(d3, CLIP_);
    double pcx = d0*ww + cx, pcy = d1*hh + cy;
    double pw = exp(dw)*ww, ph = exp(dh)*hh;
    x1 = pcx - 0.5*pw; y1 = pcy - 0.5*ph;
    x2 = pcx + 0.5*pw; y2 = pcy + 0.5*ph;
    x1 = fmin(fmax(x1, 0.0), IMG_);
    y1 = fmin(fmax(y1, 0.0), IMG_);
    x2 = fmin(fmax(x2, 0.0), IMG_);
    y2 = fmin(fmax(y2, 0.0), IMG_);
}

// ---------------- Phase A: raw-score histogram (obj only, float4) -----------
__global__ void k_hist(const float* __restrict__ obj, unsigned int* __restrict__ hist)
{
    __shared__ unsigned int lh[BINS];
    const int n = blockIdx.y;
    for (int i = threadIdx.x; i < BINS; i += blockDim.x) lh[i] = 0;
    __syncthreads();
    const float4* objq = (const float4*)(obj + (size_t)n * M_);
    for (int it = 0; it < 32; ++it) {
        int q = blockIdx.x * 8192 + it * 256 + threadIdx.x;   // [0, 245760)
        float4 v = objq[q];
        atomicAdd(&lh[ord32(v.x) >> BSH], 1u);
        atomicAdd(&lh[ord32(v.y) >> BSH], 1u);
        atomicAdd(&lh[ord32(v.z) >> BSH], 1u);
        atomicAdd(&lh[ord32(v.w) >> BSH], 1u);
    }
    __syncthreads();
    for (int i = threadIdx.x; i < BINS; i += blockDim.x) {
        unsigned int c = lh[i];
        if (c) atomicAdd(&hist[n*BINS + i], c);
    }
}

// ---------------- Phase B: threshold bin per image (parallel suffix) --------
__global__ void k_findT(const unsigned int* __restrict__ hist, unsigned int* __restrict__ T)
{
    __shared__ unsigned int csum[256];
    const int n = blockIdx.x;
    const int tid = threadIdx.x;
    unsigned int s = 0;
    int hi = BINS - 1 - tid*32;
    for (int i = 0; i < 32; ++i) s += hist[n*BINS + hi - i];
    csum[tid] = s;
    __syncthreads();
    if (tid == 0) {
        unsigned int cum = 0; int c = 0;
        for (; c < 256; ++c) { if (cum + csum[c] >= (unsigned)KMAJ) break; cum += csum[c]; }
        if (c == 256) { T[n] = 0; return; }
        int hi2 = BINS - 1 - c*32;
        unsigned int cum2 = cum; int b = hi2;
        for (int i = 0; i < 32; ++i) {
            b = hi2 - i;
            cum2 += hist[n*BINS + b];
            if (cum2 >= (unsigned)KMAJ) break;
        }
        if (cum2 > (unsigned)CAP && b < BINS-1) b = b + 1;  // overflow guard
        T[n] = (unsigned int)b;
    }
}

// ---------------- Phase C: collect candidates, block-aggregated -------------
__global__ void k_collect(const float* __restrict__ obj, const float* __restrict__ breg,
                          const float* __restrict__ anchors, const unsigned int* __restrict__ T,
                          unsigned int* __restrict__ cnt, uint64_t* __restrict__ cand)
{
    __shared__ uint64_t buf[CBUF];
    __shared__ unsigned int lcnt, gbase;
    const int n = blockIdx.y;
    const unsigned int Tn = T[n];
    if (threadIdx.x == 0) lcnt = 0;
    __syncthreads();
    const float4* objq = (const float4*)(obj + (size_t)n * M_);
    for (int it = 0; it < 32; ++it) {
        int q = blockIdx.x * 8192 + it * 256 + threadIdx.x;   // [0, 245760)
        float4 v = objq[q];
        int a = q >> 14;            // 16384 quads per anchor-slice
        int hwq = q & 16383;
        #pragma unroll
        for (int e = 0; e < 4; ++e) {
            float s = (e==0) ? v.x : (e==1) ? v.y : (e==2) ? v.z : v.w;
            unsigned int o = ord32(s);
            if ((o >> BSH) < Tn) continue;
            int hw = hwq*4 + e;
            int m = hw*15 + a;
            double x1,y1,x2,y2;
            decode_box(breg, anchors, n, a, hw, m, x1,y1,x2,y2);
            if (!((x2 - x1 >= MINSZ_) && (y2 - y1 >= MINSZ_))) continue;
            uint64_t key = ((uint64_t)o << 32) | (uint32_t)(~(uint32_t)m);
            unsigned int p = atomicAdd(&lcnt, 1u);
            if (p < CBUF) buf[p] = key;
            else {
                unsigned int g = atomicAdd(&cnt[n*32], 1u);
                if (g < CAP) cand[(size_t)n*CAP + g] = key;
            }
        }
    }
    __syncthreads();
    if (threadIdx.x == 0) {
        unsigned int c = min(lcnt, (unsigned int)CBUF);
        gbase = atomicAdd(&cnt[n*32], c);
    }
    __syncthreads();
    unsigned int c = min(lcnt, (unsigned int)CBUF);
    for (unsigned int i = threadIdx.x; i < c; i += 256) {
        unsigned int g = gbase + i;
        if (g < CAP) cand[(size_t)n*CAP + g] = buf[i];
    }
}

// ---------------- Phase D1: sort each 1024-chunk in place (desc) ------------
__global__ void k_sort1k(uint64_t* __restrict__ cand, const unsigned int* __restrict__ cnt)
{
    __shared__ uint64_t s[1024];
    const int n = blockIdx.y, c = blockIdx.x;
    unsigned int cn = cnt[n*32]; if (cn > CAP) cn = CAP;
    uint64_t* base = cand + (size_t)n*CAP + c*1024;
    const int rem = (int)cn - c*1024;
    for (int i = threadIdx.x; i < 1024; i += blockDim.x)
        s[i] = (i < rem) ? base[i] : 0ull;
    __syncthreads();
    for (int k = 2; k <= 1024; k <<= 1) {
        for (int j = k >> 1; j > 0; j >>= 1) {
            for (int i = threadIdx.x; i < 1024; i += blockDim.x) {
                int l = i ^ j;
                if (l > i) {
                    uint64_t A = s[i], B = s[l];
                    bool up = ((i & k) == 0);       // descending overall
                    if ((A < B) == up) { s[i] = B; s[l] = A; }
                }
            }
            __syncthreads();
        }
    }
    for (int i = threadIdx.x; i < 1024; i += blockDim.x)
        base[i] = s[i];
}

// ---------------- Phase D2: merge two sorted-1024 runs -> sorted 2048 -------
__global__ void k_merge1(const uint64_t* __restrict__ cand, uint64_t* __restrict__ runs1)
{
    __shared__ uint64_t s[2048];
    const int n = blockIdx.y, jb = blockIdx.x;
    const uint64_t* A = cand + (size_t)n*CAP + (2*jb)*1024;
    const uint64_t* B = cand + (size_t)n*CAP + (2*jb+1)*1024;
    for (int i = threadIdx.x; i < 1024; i += blockDim.x) {
        uint64_t a = A[i], b = B[1023 - i];
        s[i]        = (a > b) ? a : b;
        s[i + 1024] = (a > b) ? b : a;
    }
    __syncthreads();
    for (int j = 512; j > 0; j >>= 1) {
        for (int i = threadIdx.x; i < 2048; i += blockDim.x) {
            int l = i ^ j;
            if (l > i) {
                uint64_t A2 = s[i], B2 = s[l];
                if (A2 < B2) { s[i] = B2; s[l] = A2; }
            }
        }
        __syncthreads();
    }
    uint64_t* dst = runs1 + ((size_t)n*4 + jb)*2048;
    for (int i = threadIdx.x; i < 2048; i += blockDim.x)
        dst[i] = s[i];
}

// ---------------- Phase D3/D4: truncating merge of two sorted-2048 ----------
__device__ __forceinline__ void trunc_merge_body(
    const uint64_t* __restrict__ A, const uint64_t* __restrict__ B, uint64_t* s)
{
    for (int i = threadIdx.x; i < 2048; i += blockDim.x) {
        uint64_t a = A[i], b = B[2047 - i];
        s[i] = (a > b) ? a : b;
    }
    __syncthreads();
    for (int j = 1024; j > 0; j >>= 1) {
        for (int i = threadIdx.x; i < 2048; i += blockDim.x) {
            int l = i ^ j;
            if (l > i) {
                uint64_t A2 = s[i], B2 = s[l];
                if (A2 < B2) { s[i] = B2; s[l] = A2; }
            }
        }
        __syncthreads();
    }
}

__global__ void k_merge2(const uint64_t* __restrict__ runs1, uint64_t* __restrict__ runs2)
{
    __shared__ uint64_t s[2048];
    const int n = blockIdx.y, jb = blockIdx.x;
    trunc_merge_body(runs1 + ((size_t)n*4 + 2*jb)*2048,
                     runs1 + ((size_t)n*4 + 2*jb + 1)*2048, s);
    uint64_t* dst = runs2 + ((size_t)n*2 + jb)*2048;
    for (int i = threadIdx.x; i < 2048; i += blockDim.x)
        dst[i] = s[i];
}

// ---------------- Phase D4+E fused: final merge + f64 decode of top-K -------
__global__ void k_merge3_decode(const uint64_t* __restrict__ runs2,
                                const float* __restrict__ obj,
                                const float* __restrict__ breg,
                                const float* __restrict__ anchors,
                                double* __restrict__ boxes, double* __restrict__ probs,
                                int K)
{
    __shared__ uint64_t s[2048];
    const int n = blockIdx.x;
    trunc_merge_body(runs2 + ((size_t)n*2)*2048,
                     runs2 + ((size_t)n*2 + 1)*2048, s);
    for (int i = threadIdx.x; i < K; i += blockDim.x) {
        unsigned int m = ~((uint32_t)s[i]);
        int t = n*K + i;
        if (m >= (unsigned int)M_) {   // defensive
            boxes[(size_t)t*4+0]=0.0; boxes[(size_t)t*4+1]=0.0;
            boxes[(size_t)t*4+2]=0.0; boxes[(size_t)t*4+3]=0.0;
            probs[t] = -1000000000.0;
            continue;
        }
        int a = (int)(m % 15u);
        int hw = (int)(m / 15u);
        double x1,y1,x2,y2;
        decode_box(breg, anchors, n, a, hw, (int)m, x1,y1,x2,y2);
        double* bx = boxes + (size_t)t*4;
        bx[0]=x1; bx[1]=y1; bx[2]=x2; bx[3]=y2;
        float sc = obj[((size_t)(n*15 + a)) * 65536 + hw];
        probs[t] = 1.0 / (1.0 + exp(-(double)sc));
    }
}

// ---------------- Phase F: suppression bits, 128x128 pair tiles -------------
__global__ void k_sup(const double* __restrict__ boxes, uint64_t* __restrict__ sup, int K)
{
    __shared__ double jb[128][5];    // x1,y1,x2,y2,area
    const int n = blockIdx.y;
    const int ntiles = (K + 127) >> 7;
    int p = blockIdx.x, ti = 0, rem = ntiles;
    while (p >= rem) { p -= rem; ++ti; --rem; }
    const int tj = ti + p;

    const int rowsj = min(128, K - tj*128);
    for (int x = threadIdx.x; x < rowsj*4; x += 256)
        jb[x >> 2][x & 3] = boxes[(((size_t)n*K) + tj*128)*4 + x];
    __syncthreads();
    if (threadIdx.x < (unsigned)rowsj)
        jb[threadIdx.x][4] = (jb[threadIdx.x][2]-jb[threadIdx.x][0]) *
                             (jb[threadIdx.x][3]-jb[threadIdx.x][1]);
    __syncthreads();

    const int il = threadIdx.x >> 1;
    const int word = threadIdx.x & 1;
    const int i = ti*128 + il;
    if (i >= K) return;

    const double* bi = boxes + (((size_t)n*K) + i)*4;
    double ix1=bi[0], iy1=bi[1], ix2=bi[2], iy2=bi[3];
    double ai = (ix2-ix1)*(iy2-iy1);

    uint64_t bits = 0;
    const int jb0 = word*64;
    const int jlim = min(rowsj - jb0, 64);   // clamp word 0 to 64 cols
    const int jg0 = tj*128 + jb0;
    for (int b = 0; b < jlim; ++b) {
        int j = jg0 + b;
        if (j <= i) continue;
        double jx1=jb[jb0+b][0], jy1=jb[jb0+b][1], jx2=jb[jb0+b][2], jy2=jb[jb0+b][3];
        double aj = jb[jb0+b][4];
        double lx = fmax(ix1, jx1), ly = fmax(iy1, jy1);
        double rx = fmin(ix2, jx2), ry = fmin(iy2, jy2);
        double wx = fmax(rx - lx, 0.0), wy = fmax(ry - ly, 0.0);
        double inter = wx * wy;
        double iou = inter / (ai + aj - inter);
        if (iou > NMST_) bits |= (1ull << b);
    }
    sup[(((size_t)n*K) + i)*WPR + (tj*2 + word)] = bits;
}

// ---------------- Phase G: greedy NMS, 128-row chunks (16 barriers) ---------
// One block per image, 256 threads. Wave 0 resolves 128 rows per phase:
// loop1 (rows 0..63) updates BOTH alive words a0 (word 2c) and a1 (word
// 2c+1); loop2 (rows 64..127) updates a1 — exactly the sequential greedy
// order. pend then ORs all 128 rows' suppression (gated by final a0/a1)
// into future words. Waves 1-3 stage chunk c+1 (triangle skip: words>=2c+2).
// LDS layout: buf[2][128][32] packed 64 KiB with per-row word-slot swizzle
// (w stored at slot (w+row)&31) — applied identically on write, diag read,
// and pend read (both-sides-or-neither). Keep-mask broadcast reuses buf.
// All readlane results (uint32_t)-armored before widening (R5 post-mortem).
__global__ void __launch_bounds__(256) k_nms_out(
    const uint64_t* __restrict__ sup, const double* __restrict__ boxes,
    const double* __restrict__ probs, float* __restrict__ out, int K)
{
    __shared__ uint64_t buf[2][CH][WPR];     // 65536 B exactly
    const int n = blockIdx.x;
    const int tid = threadIdx.x;
    const int nch = (K + CH - 1) >> 7;       // 16 for K=2000

    uint64_t keepw = 0;
    if (tid < WPR) {
        int base = tid * 64;
        if (base + 64 <= K) keepw = ~0ull;
        else if (base < K)  keepw = (~0ull) >> (64 - (K - base));
    }

    // prologue: stage chunk 0 fully (all words), swizzled
    {
        const int rows = min(CH, K);
        const int tot = rows * WPR;          // 4096
        const uint64_t* src = sup + ((size_t)n*K)*WPR;
        uint64_t tmp[16];
        #pragma unroll
        for (int k = 0; k < 16; ++k) {
            int x = tid + 256*k;
            tmp[k] = (x < tot) ? src[x] : 0ull;
        }
        #pragma unroll
        for (int k = 0; k < 16; ++k) {
            int x = tid + 256*k;
            if (x < tot) {
                int row = x >> 5, w = x & 31;
                buf[0][row][(w + row) & 31] = tmp[k];
            }
        }
    }
    __syncthreads();

    for (int c = 0; c < nch; ++c) {
        const int cur = c & 1;
        const int w0 = 2 * c;
        // waves 1-3: prefetch chunk c+1, words >= 2(c+1) (triangle skip)
        if (tid >= 64 && c + 1 < nch) {
            const int c1 = c + 1;
            const int i0 = c1 * CH;
            const int rows = min(CH, K - i0);
            const uint64_t* src = sup + (((size_t)n*K) + i0)*WPR;
            const int t = tid - 64;          // [0,192)
            const int w = 2*c1 + (t & 31);
            const int rg = t >> 5;           // [0,6)
            uint64_t tmp[22];
            #pragma unroll
            for (int k = 0; k < 22; ++k) {
                int row = rg + 6*k;
                bool p = (w < WPR) && (row < rows);
                tmp[k] = p ? src[(size_t)row*WPR + w] : 0ull;
            }
            #pragma unroll
            for (int k = 0; k < 22; ++k) {
                int row = rg + 6*k;
                if ((w < WPR) && (row < rows))
                    buf[cur ^ 1][row][(w + row) & 31] = tmp[k];
            }
        }
        if (tid < 64) {
            // preload diagonal-block words (swizzled slots; (w+64+t)&31==(w+t)&31)
            uint64_t d0 = buf[cur][tid]     [(w0     + tid) & 31];  // row tid,    word 2c
            uint64_t d1 = buf[cur][tid]     [(w0 + 1 + tid) & 31];  // row tid,    word 2c+1
            uint64_t e1 = buf[cur][64 + tid][(w0 + 1 + tid) & 31];  // row 64+tid, word 2c+1
            uint32_t d0lo = (uint32_t)d0, d0hi = (uint32_t)(d0 >> 32);
            uint32_t d1lo = (uint32_t)d1, d1hi = (uint32_t)(d1 >> 32);
            uint32_t e1lo = (uint32_t)e1, e1hi = (uint32_t)(e1 >> 32);
            uint32_t alo0 = (uint32_t)__builtin_amdgcn_readlane((uint32_t)keepw, w0);
            uint32_t ahi0 = (uint32_t)__builtin_amdgcn_readlane((uint32_t)(keepw >> 32), w0);
            uint32_t alo1 = (uint32_t)__builtin_amdgcn_readlane((uint32_t)keepw, w0 + 1);
            uint32_t ahi1 = (uint32_t)__builtin_amdgcn_readlane((uint32_t)(keepw >> 32), w0 + 1);
            uint64_t a0 = ((uint64_t)ahi0 << 32) | (uint64_t)alo0;
            uint64_t a1 = ((uint64_t)ahi1 << 32) | (uint64_t)alo1;
            // loop1: rows 0..63 — update a0 (own word) AND a1 (next word)
            #pragma unroll
            for (int r = 0; r < 64; ++r) {
                uint64_t r0 =
                    ((uint64_t)(uint32_t)__builtin_amdgcn_readlane(d0hi, r) << 32)
                  |  (uint64_t)(uint32_t)__builtin_amdgcn_readlane(d0lo, r);
                uint64_t r1 =
                    ((uint64_t)(uint32_t)__builtin_amdgcn_readlane(d1hi, r) << 32)
                  |  (uint64_t)(uint32_t)__builtin_amdgcn_readlane(d1lo, r);
                uint64_t msk = (uint64_t)0 - ((a0 >> r) & 1ull);
                a0 &= ~(r0 & msk);
                a1 &= ~(r1 & msk);
            }
            // loop2: rows 64..127 — update a1 (their own word)
            #pragma unroll
            for (int r = 0; r < 64; ++r) {
                uint64_t r1 =
                    ((uint64_t)(uint32_t)__builtin_amdgcn_readlane(e1hi, r) << 32)
                  |  (uint64_t)(uint32_t)__builtin_amdgcn_readlane(e1lo, r);
                uint64_t msk = (uint64_t)0 - ((a1 >> r) & 1ull);
                a1 &= ~(r1 & msk);
            }
            if (tid == w0)     keepw = a0;
            if (tid == w0 + 1) keepw = a1;
            // pend OR over all 128 rows (gated by final a0/a1), halves combined
            const int w = tid & 31;
            const int rbase = (tid >> 5) * 64;           // 0 or 64
            const uint64_t sel = (tid & 32) ? a1 : a0;
            uint64_t pend = 0;
            #pragma unroll
            for (int rr = 0; rr < 64; ++rr) {
                int row = rbase + rr;
                uint64_t msk = (uint64_t)0 - ((sel >> rr) & 1ull);
                pend |= buf[cur][row][(w + row) & 31] & msk;
            }
            pend |= (uint64_t)__shfl_xor((unsigned long long)pend, 32, 64);
            if (tid < WPR && tid > w0 + 1) keepw &= ~pend;
        }
        __syncthreads();
    }

    // broadcast keep mask via LDS reuse
    if (tid < WPR) buf[0][0][tid] = keepw;
    __syncthreads();

    // fused output write
    for (int k = tid; k < K; k += 256) {
        uint64_t w = buf[0][0][k >> 6];
        double f = ((w >> (k & 63)) & 1ull) ? 1.0 : 0.0;
        const double* b = boxes + (((size_t)n*K) + k)*4;
        float* o = out + (((size_t)n*K) + k)*5;
        o[0] = (float)(b[0]*f);
        o[1] = (float)(b[1]*f);
        o[2] = (float)(b[2]*f);
        o[3] = (float)(b[3]*f);
        o[4] = (float)(probs[(size_t)n*K + k]*f);
    }
}

extern "C" void kernel_launch(void* const* d_in, const int* in_sizes, int n_in,
                              void* d_out, int out_size, void* d_ws, size_t ws_size,
                              hipStream_t stream)
{
    const float* obj     = (const float*)d_in[0];
    const float* breg    = (const float*)d_in[1];
    const float* anchors = (const float*)d_in[2];
    float* out = (float*)d_out;

    const int K = out_size / (N_ * 5);      // 2000

    // workspace layout (bytes); cand/runs1/runs2 overlay sup (disjoint
    // lifetimes: all sort traffic completes before k_sup writes sup, and
    // every sup word k_nms_out consumes is written by k_sup each call)
    char* ws = (char*)d_ws;
    unsigned int* hist  = (unsigned int*)(ws + 0);          // 256 KiB
    unsigned int* T     = (unsigned int*)(ws + 262144);
    unsigned int* cnt   = (unsigned int*)(ws + 262272);     // 8 * 128 B padded
    double*       boxes = (double*)      (ws + 327680);     // 512 KB
    double*       probs = (double*)      (ws + 839680);     // 128 KB
    uint64_t*     sup   = (uint64_t*)    (ws + 970752);     // 4 MB
    uint64_t*     cand  = (uint64_t*)    (ws + 970752);            // overlay: 512 KB
    uint64_t*     runs1 = (uint64_t*)    (ws + 970752 + 524288);   // overlay: 512 KB
    uint64_t*     runs2 = (uint64_t*)    (ws + 970752 + 1048576);  // overlay: 256 KB

    hipMemsetAsync(ws, 0, 263296, stream);  // zero hist + T + cnt every call

    dim3 gH(30, N_);
    k_hist<<<gH, 256, 0, stream>>>(obj, hist);
    k_findT<<<N_, 256, 0, stream>>>(hist, T);
    k_collect<<<gH, 256, 0, stream>>>(obj, breg, anchors, T, cnt, cand);
    k_sort1k<<<dim3(8, N_), 512, 0, stream>>>(cand, cnt);
    k_merge1<<<dim3(4, N_), 1024, 0, stream>>>(cand, runs1);
    k_merge2<<<dim3(2, N_), 1024, 0, stream>>>(runs1, runs2);
    k_merge3_decode<<<N_, 1024, 0, stream>>>(runs2, obj, breg, anchors, boxes, probs, K);
    const int ntiles = (K + 127) >> 7;
    dim3 gS(ntiles*(ntiles+1)/2, N_);
    k_sup<<<gS, 256, 0, stream>>>(boxes, sup, K);
    k_nms_out<<<N_, 256, 0, stream>>>(sup, boxes, probs, out, K);
}

// Round 13
// 227.673 us; speedup vs baseline: 1.0213x; 1.0213x over previous
//
#include <hip/hip_runtime.h>
#include <stdint.h>

// Problem constants (fixed by setup_inputs)
#define N_    8
#define A_    15
#define H_    256
#define W_    256
#define M_    (A_*H_*W_)      // 983040 anchors per image
#define BINS  8192
#define BSH   19              // ord32 >> 19 = top 13 bits
#define KMAJ  3200            // raw-count threshold margin over K=2000
#define CAP   8192            // candidate capacity per image
#define CBUF  2048            // per-block LDS candidate buffer
#define WPR   32              // words per keep-row = ceil(2000/64)

__device__ __constant__ double CLIP_  = 4.135166556742356;  // log(1000/16) in f64
__device__ __constant__ double IMG_   = 1024.0;
__device__ __constant__ double MINSZ_ = 1.0;
__device__ __constant__ double NMST_  = 0.7;

__device__ __forceinline__ uint32_t ord32(float s) {
    uint32_t u = __float_as_uint(s);
    return u ^ (uint32_t)(((int32_t)u >> 31) | 0x80000000u);
}

// f64 decode exactly mirroring the reference formula order (unchanged — passing)
__device__ __forceinline__ void decode_box(
    const float* __restrict__ breg, const float* __restrict__ anchors,
    int n, int a, int hw, int m,
    double& x1, double& y1, double& x2, double& y2)
{
    size_t bbase = ((size_t)(n*60 + a*4)) * 65536 + (size_t)hw;
    double d0 = (double)breg[bbase];
    double d1 = (double)breg[bbase + 65536];
    double d2 = (double)breg[bbase + 2*65536];
    double d3 = (double)breg[bbase + 3*65536];
    float4 av = *reinterpret_cast<const float4*>(anchors + (size_t)m*4);
    double a0 = (double)av.x, a1 = (double)av.y, a2 = (double)av.z, a3 = (double)av.w;
    double ww = a2 - a0, hh = a3 - a1;
    double cx = a0 + 0.5*ww, cy = a1 + 0.5*hh;
    double dw = fmin(d2, CLIP_), dh = fmin(d3, CLIP_);
    double pcx = d0*ww + cx, pcy = d1*hh + cy;
    double pw = exp(dw)*ww, ph = exp(dh)*hh;
    x1 = pcx - 0.5*pw; y1 = pcy - 0.5*ph;
    x2 = pcx + 0.5*pw; y2 = pcy + 0.5*ph;
    x1 = fmin(fmax(x1, 0.0), IMG_);
    y1 = fmin(fmax(y1, 0.0), IMG_);
    x2 = fmin(fmax(x2, 0.0), IMG_);
    y2 = fmin(fmax(y2, 0.0), IMG_);
}

// ---------------- Phase A: raw-score histogram (obj only, float4) -----------
__global__ void k_hist(const float* __restrict__ obj, unsigned int* __restrict__ hist)
{
    __shared__ unsigned int lh[BINS];
    const int n = blockIdx.y;
    for (int i = threadIdx.x; i < BINS; i += blockDim.x) lh[i] = 0;
    __syncthreads();
    const float4* objq = (const float4*)(obj + (size_t)n * M_);
    for (int it = 0; it < 32; ++it) {
        int q = blockIdx.x * 8192 + it * 256 + threadIdx.x;   // [0, 245760)
        float4 v = objq[q];
        atomicAdd(&lh[ord32(v.x) >> BSH], 1u);
        atomicAdd(&lh[ord32(v.y) >> BSH], 1u);
        atomicAdd(&lh[ord32(v.z) >> BSH], 1u);
        atomicAdd(&lh[ord32(v.w) >> BSH], 1u);
    }
    __syncthreads();
    for (int i = threadIdx.x; i < BINS; i += blockDim.x) {
        unsigned int c = lh[i];
        if (c) atomicAdd(&hist[n*BINS + i], c);
    }
}

// ---------------- Phase B: threshold bin per image (parallel suffix) --------
__global__ void k_findT(const unsigned int* __restrict__ hist, unsigned int* __restrict__ T)
{
    __shared__ unsigned int csum[256];
    const int n = blockIdx.x;
    const int tid = threadIdx.x;
    unsigned int s = 0;
    int hi = BINS - 1 - tid*32;
    for (int i = 0; i < 32; ++i) s += hist[n*BINS + hi - i];
    csum[tid] = s;
    __syncthreads();
    if (tid == 0) {
        unsigned int cum = 0; int c = 0;
        for (; c < 256; ++c) { if (cum + csum[c] >= (unsigned)KMAJ) break; cum += csum[c]; }
        if (c == 256) { T[n] = 0; return; }
        int hi2 = BINS - 1 - c*32;
        unsigned int cum2 = cum; int b = hi2;
        for (int i = 0; i < 32; ++i) {
            b = hi2 - i;
            cum2 += hist[n*BINS + b];
            if (cum2 >= (unsigned)KMAJ) break;
        }
        if (cum2 > (unsigned)CAP && b < BINS-1) b = b + 1;  // overflow guard
        T[n] = (unsigned int)b;
    }
}

// ---------------- Phase C: collect candidates, block-aggregated -------------
__global__ void k_collect(const float* __restrict__ obj, const float* __restrict__ breg,
                          const float* __restrict__ anchors, const unsigned int* __restrict__ T,
                          unsigned int* __restrict__ cnt, uint64_t* __restrict__ cand)
{
    __shared__ uint64_t buf[CBUF];
    __shared__ unsigned int lcnt, gbase;
    const int n = blockIdx.y;
    const unsigned int Tn = T[n];
    if (threadIdx.x == 0) lcnt = 0;
    __syncthreads();
    const float4* objq = (const float4*)(obj + (size_t)n * M_);
    for (int it = 0; it < 32; ++it) {
        int q = blockIdx.x * 8192 + it * 256 + threadIdx.x;   // [0, 245760)
        float4 v = objq[q];
        int a = q >> 14;            // 16384 quads per anchor-slice
        int hwq = q & 16383;
        #pragma unroll
        for (int e = 0; e < 4; ++e) {
            float s = (e==0) ? v.x : (e==1) ? v.y : (e==2) ? v.z : v.w;
            unsigned int o = ord32(s);
            if ((o >> BSH) < Tn) continue;
            int hw = hwq*4 + e;
            int m = hw*15 + a;
            double x1,y1,x2,y2;
            decode_box(breg, anchors, n, a, hw, m, x1,y1,x2,y2);
            if (!((x2 - x1 >= MINSZ_) && (y2 - y1 >= MINSZ_))) continue;
            uint64_t key = ((uint64_t)o << 32) | (uint32_t)(~(uint32_t)m);
            unsigned int p = atomicAdd(&lcnt, 1u);
            if (p < CBUF) buf[p] = key;
            else {
                unsigned int g = atomicAdd(&cnt[n*32], 1u);
                if (g < CAP) cand[(size_t)n*CAP + g] = key;
            }
        }
    }
    __syncthreads();
    if (threadIdx.x == 0) {
        unsigned int c = min(lcnt, (unsigned int)CBUF);
        gbase = atomicAdd(&cnt[n*32], c);
    }
    __syncthreads();
    unsigned int c = min(lcnt, (unsigned int)CBUF);
    for (unsigned int i = threadIdx.x; i < c; i += 256) {
        unsigned int g = gbase + i;
        if (g < CAP) cand[(size_t)n*CAP + g] = buf[i];
    }
}

// ---------------- Phase D1: sort each 1024-chunk in place (desc) ------------
__global__ void k_sort1k(uint64_t* __restrict__ cand, const unsigned int* __restrict__ cnt)
{
    __shared__ uint64_t s[1024];
    const int n = blockIdx.y, c = blockIdx.x;
    unsigned int cn = cnt[n*32]; if (cn > CAP) cn = CAP;
    uint64_t* base = cand + (size_t)n*CAP + c*1024;
    const int rem = (int)cn - c*1024;
    for (int i = threadIdx.x; i < 1024; i += blockDim.x)
        s[i] = (i < rem) ? base[i] : 0ull;
    __syncthreads();
    for (int k = 2; k <= 1024; k <<= 1) {
        for (int j = k >> 1; j > 0; j >>= 1) {
            for (int i = threadIdx.x; i < 1024; i += blockDim.x) {
                int l = i ^ j;
                if (l > i) {
                    uint64_t A = s[i], B = s[l];
                    bool up = ((i & k) == 0);       // descending overall
                    if ((A < B) == up) { s[i] = B; s[l] = A; }
                }
            }
            __syncthreads();
        }
    }
    for (int i = threadIdx.x; i < 1024; i += blockDim.x)
        base[i] = s[i];
}

// ---------------- Phase D2: merge two sorted-1024 runs -> sorted 2048 -------
__global__ void k_merge1(const uint64_t* __restrict__ cand, uint64_t* __restrict__ runs1)
{
    __shared__ uint64_t s[2048];
    const int n = blockIdx.y, jb = blockIdx.x;
    const uint64_t* A = cand + (size_t)n*CAP + (2*jb)*1024;
    const uint64_t* B = cand + (size_t)n*CAP + (2*jb+1)*1024;
    for (int i = threadIdx.x; i < 1024; i += blockDim.x) {
        uint64_t a = A[i], b = B[1023 - i];
        s[i]        = (a > b) ? a : b;
        s[i + 1024] = (a > b) ? b : a;
    }
    __syncthreads();
    for (int j = 512; j > 0; j >>= 1) {
        for (int i = threadIdx.x; i < 2048; i += blockDim.x) {
            int l = i ^ j;
            if (l > i) {
                uint64_t A2 = s[i], B2 = s[l];
                if (A2 < B2) { s[i] = B2; s[l] = A2; }
            }
        }
        __syncthreads();
    }
    uint64_t* dst = runs1 + ((size_t)n*4 + jb)*2048;
    for (int i = threadIdx.x; i < 2048; i += blockDim.x)
        dst[i] = s[i];
}

// ---------------- Phase D3/D4: truncating merge of two sorted-2048 ----------
__device__ __forceinline__ void trunc_merge_body(
    const uint64_t* __restrict__ A, const uint64_t* __restrict__ B, uint64_t* s)
{
    for (int i = threadIdx.x; i < 2048; i += blockDim.x) {
        uint64_t a = A[i], b = B[2047 - i];
        s[i] = (a > b) ? a : b;
    }
    __syncthreads();
    for (int j = 1024; j > 0; j >>= 1) {
        for (int i = threadIdx.x; i < 2048; i += blockDim.x) {
            int l = i ^ j;
            if (l > i) {
                uint64_t A2 = s[i], B2 = s[l];
                if (A2 < B2) { s[i] = B2; s[l] = A2; }
            }
        }
        __syncthreads();
    }
}

__global__ void k_merge2(const uint64_t* __restrict__ runs1, uint64_t* __restrict__ runs2)
{
    __shared__ uint64_t s[2048];
    const int n = blockIdx.y, jb = blockIdx.x;
    trunc_merge_body(runs1 + ((size_t)n*4 + 2*jb)*2048,
                     runs1 + ((size_t)n*4 + 2*jb + 1)*2048, s);
    uint64_t* dst = runs2 + ((size_t)n*2 + jb)*2048;
    for (int i = threadIdx.x; i < 2048; i += blockDim.x)
        dst[i] = s[i];
}

// ---------------- Phase D4+E fused: final merge + f64 decode of top-K -------
__global__ void k_merge3_decode(const uint64_t* __restrict__ runs2,
                                const float* __restrict__ obj,
                                const float* __restrict__ breg,
                                const float* __restrict__ anchors,
                                double* __restrict__ boxes, double* __restrict__ probs,
                                int K)
{
    __shared__ uint64_t s[2048];
    const int n = blockIdx.x;
    trunc_merge_body(runs2 + ((size_t)n*2)*2048,
                     runs2 + ((size_t)n*2 + 1)*2048, s);
    for (int i = threadIdx.x; i < K; i += blockDim.x) {
        unsigned int m = ~((uint32_t)s[i]);
        int t = n*K + i;
        if (m >= (unsigned int)M_) {   // defensive
            boxes[(size_t)t*4+0]=0.0; boxes[(size_t)t*4+1]=0.0;
            boxes[(size_t)t*4+2]=0.0; boxes[(size_t)t*4+3]=0.0;
            probs[t] = -1000000000.0;
            continue;
        }
        int a = (int)(m % 15u);
        int hw = (int)(m / 15u);
        double x1,y1,x2,y2;
        decode_box(breg, anchors, n, a, hw, (int)m, x1,y1,x2,y2);
        double* bx = boxes + (size_t)t*4;
        bx[0]=x1; bx[1]=y1; bx[2]=x2; bx[3]=y2;
        float sc = obj[((size_t)(n*15 + a)) * 65536 + hw];
        probs[t] = 1.0 / (1.0 + exp(-(double)sc));
    }
}

// ---------------- Phase F: suppression bits, 128x128 pair tiles -------------
__global__ void k_sup(const double* __restrict__ boxes, uint64_t* __restrict__ sup, int K)
{
    __shared__ double jb[128][5];    // x1,y1,x2,y2,area
    const int n = blockIdx.y;
    const int ntiles = (K + 127) >> 7;
    int p = blockIdx.x, ti = 0, rem = ntiles;
    while (p >= rem) { p -= rem; ++ti; --rem; }
    const int tj = ti + p;

    const int rowsj = min(128, K - tj*128);
    for (int x = threadIdx.x; x < rowsj*4; x += 256)
        jb[x >> 2][x & 3] = boxes[(((size_t)n*K) + tj*128)*4 + x];
    __syncthreads();
    if (threadIdx.x < (unsigned)rowsj)
        jb[threadIdx.x][4] = (jb[threadIdx.x][2]-jb[threadIdx.x][0]) *
                             (jb[threadIdx.x][3]-jb[threadIdx.x][1]);
    __syncthreads();

    const int il = threadIdx.x >> 1;
    const int word = threadIdx.x & 1;
    const int i = ti*128 + il;
    if (i >= K) return;

    const double* bi = boxes + (((size_t)n*K) + i)*4;
    double ix1=bi[0], iy1=bi[1], ix2=bi[2], iy2=bi[3];
    double ai = (ix2-ix1)*(iy2-iy1);

    uint64_t bits = 0;
    const int jb0 = word*64;
    const int jlim = min(rowsj - jb0, 64);   // clamp word 0 to 64 cols
    const int jg0 = tj*128 + jb0;
    for (int b = 0; b < jlim; ++b) {
        int j = jg0 + b;
        if (j <= i) continue;
        double jx1=jb[jb0+b][0], jy1=jb[jb0+b][1], jx2=jb[jb0+b][2], jy2=jb[jb0+b][3];
        double aj = jb[jb0+b][4];
        double lx = fmax(ix1, jx1), ly = fmax(iy1, jy1);
        double rx = fmin(ix2, jx2), ry = fmin(iy2, jy2);
        double wx = fmax(rx - lx, 0.0), wy = fmax(ry - ly, 0.0);
        double inter = wx * wy;
        double iou = inter / (ai + aj - inter);
        if (iou > NMST_) bits |= (1ull << b);
    }
    sup[(((size_t)n*K) + i)*WPR + (tj*2 + word)] = bits;
}

// ---------------- Phase G: greedy NMS (R10 structure; batched readlanes) ----
// One block per image, 256 threads. Wave 0 resolves 64-row chunks; waves 1-3
// stage chunk c+1 with triangle-skip (words >= c+1 only). Resolve is R10's
// proven form, restructured into 8-row batches: 16 independent readlanes
// issued as a group, then 8 dependent steps — lets the scheduler overlap
// batch b+1's readlanes (VALU) with batch b's serial chain, hiding the
// VALU->SALU SGPR-forwarding hazard. Identical math to R10.
// All readlane results (uint32_t)-armored before widening (R5 post-mortem).
#define RL_(r) (((uint64_t)(uint32_t)__builtin_amdgcn_readlane(dhi,(r)) << 32) \
              |  (uint64_t)(uint32_t)__builtin_amdgcn_readlane(dlo,(r)))
#define ST_(r, rw) { uint64_t msk_ = (uint64_t)0 - ((alive >> (r)) & 1ull); \
                     alive &= ~((rw) & msk_); }
__global__ void __launch_bounds__(256) k_nms_out(
    const uint64_t* __restrict__ sup, const double* __restrict__ boxes,
    const double* __restrict__ probs, float* __restrict__ out, int K)
{
    __shared__ uint64_t buf[2][64][WPR+1];   // +1 pad: diag read 64-way -> ~4-way
    __shared__ uint64_t keep_lds[WPR];
    const int n = blockIdx.x;
    const int tid = threadIdx.x;
    const int nch = (K + 63) >> 6;           // 32 for K=2000

    uint64_t keepw = 0;
    if (tid < WPR) {
        int base = tid * 64;
        if (base + 64 <= K) keepw = ~0ull;
        else if (base < K)  keepw = (~0ull) >> (64 - (K - base));
    }

    // stage chunk 0 with all threads (full width; register-staged, unrolled)
    {
        const int tot = min(64, K) * WPR;
        const uint64_t* src = sup + ((size_t)n*K)*WPR;
        uint64_t tmp[8];
        #pragma unroll
        for (int k = 0; k < 8; ++k) {
            int x = tid + 256*k;
            tmp[k] = (x < tot) ? src[x] : 0ull;
        }
        #pragma unroll
        for (int k = 0; k < 8; ++k) {
            int x = tid + 256*k;
            if (x < tot) buf[0][x >> 5][x & 31] = tmp[k];
        }
    }
    __syncthreads();

    for (int c = 0; c < nch; ++c) {
        const int cur = c & 1;
        // waves 1-3: prefetch chunk c+1, words >= c+1 only (triangle skip)
        if (tid >= 64 && c + 1 < nch) {
            const int c1 = c + 1;
            const int i0 = c1 * 64;
            const int rows = min(64, K - i0);
            const uint64_t* src = sup + (((size_t)n*K) + i0)*WPR;
            const int t = tid - 64;          // [0,192)
            const int lane_w = t & 31;       // word offset within row
            const int rg = t >> 5;           // row group [0,6)
            const int w = c1 + lane_w;       // absolute word index
            uint64_t tmp[11];
            #pragma unroll
            for (int k = 0; k < 11; ++k) {
                int row = rg + 6*k;
                bool p = (w < WPR) && (row < rows);
                tmp[k] = p ? src[(size_t)row*WPR + w] : 0ull;
            }
            #pragma unroll
            for (int k = 0; k < 11; ++k) {
                int row = rg + 6*k;
                if ((w < WPR) && (row < rows)) buf[cur ^ 1][row][w] = tmp[k];
            }
        }
        if (tid < 64) {
            // --- diagonal resolve: uniform alive (SGPR) + batched readlanes ---
            uint64_t diag = buf[cur][tid][c];
            uint32_t dlo = (uint32_t)diag;
            uint32_t dhi = (uint32_t)(diag >> 32);
            uint32_t alo = (uint32_t)__builtin_amdgcn_readlane((uint32_t)keepw, c);
            uint32_t ahi = (uint32_t)__builtin_amdgcn_readlane((uint32_t)(keepw >> 32), c);
            uint64_t alive = ((uint64_t)ahi << 32) | (uint64_t)alo;
            #pragma unroll
            for (int b = 0; b < 8; ++b) {
                const int r0b = b * 8;
                uint64_t w0_ = RL_(r0b + 0);
                uint64_t w1_ = RL_(r0b + 1);
                uint64_t w2_ = RL_(r0b + 2);
                uint64_t w3_ = RL_(r0b + 3);
                uint64_t w4_ = RL_(r0b + 4);
                uint64_t w5_ = RL_(r0b + 5);
                uint64_t w6_ = RL_(r0b + 6);
                uint64_t w7_ = RL_(r0b + 7);
                ST_(r0b + 0, w0_);
                ST_(r0b + 1, w1_);
                ST_(r0b + 2, w2_);
                ST_(r0b + 3, w3_);
                ST_(r0b + 4, w4_);
                ST_(r0b + 5, w5_);
                ST_(r0b + 6, w6_);
                ST_(r0b + 7, w7_);
            }
            if (tid == c) keepw = alive;
            // --- pend OR over kept rows, split across wave halves ---
            const int w = tid & 31;
            const int r0 = (tid >> 5) * 32;
            uint64_t pend = 0;
            #pragma unroll
            for (int rr = 0; rr < 32; ++rr) {
                int r = r0 + rr;
                uint64_t msk = (uint64_t)0 - ((alive >> r) & 1ull);
                pend |= buf[cur][r][w] & msk;
            }
            pend |= (uint64_t)__shfl_xor((unsigned long long)pend, 32, 64);
            if (tid < WPR && tid > c) keepw &= ~pend;
        }
        __syncthreads();
    }

    if (tid < WPR) keep_lds[tid] = keepw;
    __syncthreads();

    // fused output write
    for (int k = tid; k < K; k += 256) {
        uint64_t w = keep_lds[k >> 6];
        double f = ((w >> (k & 63)) & 1ull) ? 1.0 : 0.0;
        const double* b = boxes + (((size_t)n*K) + k)*4;
        float* o = out + (((size_t)n*K) + k)*5;
        o[0] = (float)(b[0]*f);
        o[1] = (float)(b[1]*f);
        o[2] = (float)(b[2]*f);
        o[3] = (float)(b[3]*f);
        o[4] = (float)(probs[(size_t)n*K + k]*f);
    }
}

extern "C" void kernel_launch(void* const* d_in, const int* in_sizes, int n_in,
                              void* d_out, int out_size, void* d_ws, size_t ws_size,
                              hipStream_t stream)
{
    const float* obj     = (const float*)d_in[0];
    const float* breg    = (const float*)d_in[1];
    const float* anchors = (const float*)d_in[2];
    float* out = (float*)d_out;

    const int K = out_size / (N_ * 5);      // 2000

    // workspace layout (bytes); cand/runs1/runs2 overlay sup (disjoint
    // lifetimes: all sort traffic completes before k_sup writes sup, and
    // every sup word k_nms_out consumes is written by k_sup each call)
    char* ws = (char*)d_ws;
    unsigned int* hist  = (unsigned int*)(ws + 0);          // 256 KiB
    unsigned int* T     = (unsigned int*)(ws + 262144);
    unsigned int* cnt   = (unsigned int*)(ws + 262272);     // 8 * 128 B padded
    double*       boxes = (double*)      (ws + 327680);     // 512 KB
    double*       probs = (double*)      (ws + 839680);     // 128 KB
    uint64_t*     sup   = (uint64_t*)    (ws + 970752);     // 4 MB
    uint64_t*     cand  = (uint64_t*)    (ws + 970752);            // overlay: 512 KB
    uint64_t*     runs1 = (uint64_t*)    (ws + 970752 + 524288);   // overlay: 512 KB
    uint64_t*     runs2 = (uint64_t*)    (ws + 970752 + 1048576);  // overlay: 256 KB

    hipMemsetAsync(ws, 0, 263296, stream);  // zero hist + T + cnt every call

    dim3 gH(30, N_);
    k_hist<<<gH, 256, 0, stream>>>(obj, hist);
    k_findT<<<N_, 256, 0, stream>>>(hist, T);
    k_collect<<<gH, 256, 0, stream>>>(obj, breg, anchors, T, cnt, cand);
    k_sort1k<<<dim3(8, N_), 512, 0, stream>>>(cand, cnt);
    k_merge1<<<dim3(4, N_), 1024, 0, stream>>>(cand, runs1);
    k_merge2<<<dim3(2, N_), 1024, 0, stream>>>(runs1, runs2);
    k_merge3_decode<<<N_, 1024, 0, stream>>>(runs2, obj, breg, anchors, boxes, probs, K);
    const int ntiles = (K + 127) >> 7;
    dim3 gS(ntiles*(ntiles+1)/2, N_);
    k_sup<<<gS, 256, 0, stream>>>(boxes, sup, K);
    k_nms_out<<<N_, 256, 0, stream>>>(sup, boxes, probs, out, K);
}